// Round 1
// baseline (2776.821 us; speedup 1.0000x reference)
//
#include <hip/hip_runtime.h>

constexpr int N_NODES  = 100000;
constexpr int N_EDGES  = 3200000;
constexpr int N_GRAPHS = 64;

// ---------------- degree / normalization ----------------

__global__ void count_deg_kernel(const int* __restrict__ dst, float* __restrict__ deg) {
    int e = blockIdx.x * blockDim.x + threadIdx.x;
    if (e < N_EDGES) atomicAdd(&deg[dst[e]], 1.0f);
}

__global__ void finish_dis_kernel(float* __restrict__ deg) {
    int i = blockIdx.x * blockDim.x + threadIdx.x;
    if (i < N_NODES) deg[i] = 1.0f / sqrtf(deg[i] + 1.0f);  // +1 self loop; precise
}

// ---------------- per-layer kernels ----------------

// g[i,:] = (in[i,:] @ W) * dis[i];  acc initialized to g (self-loop term)
template<int FIN, int FOUT>
__global__ void lin_kernel(const float* __restrict__ in, const float* __restrict__ W,
                           const float* __restrict__ dis,
                           float* __restrict__ g, float* __restrict__ acc) {
    int i = blockIdx.x * blockDim.x + threadIdx.x;
    if (i >= N_NODES) return;
    float xin[FIN];
#pragma unroll
    for (int k = 0; k < FIN; ++k) xin[k] = in[(size_t)i * FIN + k];
    float d = dis[i];
#pragma unroll
    for (int f = 0; f < FOUT; ++f) {
        float s = 0.f;
#pragma unroll
        for (int k = 0; k < FIN; ++k) s = fmaf(xin[k], W[k * FOUT + f], s);
        s *= d;
        g[(size_t)i * FOUT + f]   = s;
        acc[(size_t)i * FOUT + f] = s;
    }
}

// acc[dst,:] += g[src,:] — one thread per (edge, 4-feature chunk)
template<int FOUT>
__global__ void edge_kernel(const int* __restrict__ src, const int* __restrict__ dst,
                            const float* __restrict__ g, float* __restrict__ acc) {
    constexpr int CH = FOUT / 4;
    long long t = (long long)blockIdx.x * blockDim.x + threadIdx.x;
    int e = (int)(t / CH);
    int c = (int)(t % CH);
    if (e >= N_EDGES) return;
    int s = src[e], d = dst[e];
    float4 gv = *reinterpret_cast<const float4*>(&g[(size_t)s * FOUT + c * 4]);
    float* ap = &acc[(size_t)d * FOUT + c * 4];
    atomicAdd(ap + 0, gv.x);
    atomicAdd(ap + 1, gv.y);
    atomicAdd(ap + 2, gv.z);
    atomicAdd(ap + 3, gv.w);
}

// out = relu(dis[i]*acc + b[f])
template<int FOUT>
__global__ void post_kernel(const float* __restrict__ acc, const float* __restrict__ dis,
                            const float* __restrict__ b, float* __restrict__ out) {
    int t = blockIdx.x * blockDim.x + threadIdx.x;
    if (t >= N_NODES * FOUT) return;
    int i = t / FOUT, f = t % FOUT;
    out[t] = fmaxf(fmaf(dis[i], acc[t], b[f]), 0.f);
}

// ---------------- pooling + final linear ----------------

// pool[0..511] = per-graph feature sums (64x8); pool[512..575] = counts
__global__ void pool_kernel(const float* __restrict__ h, const int* __restrict__ batch,
                            float* __restrict__ pool) {
    __shared__ float lsum[N_GRAPHS * 8];
    __shared__ float lcnt[N_GRAPHS];
    int tid = threadIdx.x;
    for (int j = tid; j < N_GRAPHS * 8; j += blockDim.x) lsum[j] = 0.f;
    for (int j = tid; j < N_GRAPHS; j += blockDim.x) lcnt[j] = 0.f;
    __syncthreads();
    int i = blockIdx.x * blockDim.x + tid;
    if (i < N_NODES) {
        int gm = batch[i];
        const float4* hp = reinterpret_cast<const float4*>(&h[(size_t)i * 8]);
        float4 a = hp[0], bq = hp[1];
        atomicAdd(&lsum[gm * 8 + 0], a.x);
        atomicAdd(&lsum[gm * 8 + 1], a.y);
        atomicAdd(&lsum[gm * 8 + 2], a.z);
        atomicAdd(&lsum[gm * 8 + 3], a.w);
        atomicAdd(&lsum[gm * 8 + 4], bq.x);
        atomicAdd(&lsum[gm * 8 + 5], bq.y);
        atomicAdd(&lsum[gm * 8 + 6], bq.z);
        atomicAdd(&lsum[gm * 8 + 7], bq.w);
        atomicAdd(&lcnt[gm], 1.0f);
    }
    __syncthreads();
    for (int idx = tid; idx < N_GRAPHS * 9; idx += blockDim.x) {
        int gm = idx / 9, j = idx % 9;
        if (lcnt[gm] != 0.f) {
            if (j < 8) atomicAdd(&pool[gm * 8 + j], lsum[gm * 8 + j]);
            else       atomicAdd(&pool[512 + gm], lcnt[gm]);
        }
    }
}

__global__ void final_kernel(const float* __restrict__ pool, const float* __restrict__ Wf,
                             const float* __restrict__ bf, float* __restrict__ out) {
    int t = threadIdx.x;
    if (t >= N_GRAPHS * 3) return;
    int gm = t / 3, c = t % 3;
    float cnt = fmaxf(pool[512 + gm], 1.0f);
    float s = 0.f;
#pragma unroll
    for (int f = 0; f < 8; ++f) s = fmaf(pool[gm * 8 + f] / cnt, Wf[f * 3 + c], s);
    out[t] = s + bf[c];
}

// ---------------- launch ----------------

extern "C" void kernel_launch(void* const* d_in, const int* in_sizes, int n_in,
                              void* d_out, int out_size, void* d_ws, size_t ws_size,
                              hipStream_t stream) {
    const float* x     = (const float*)d_in[0];
    const int*   ei    = (const int*)d_in[1];
    const int*   batch = (const int*)d_in[2];
    const float* W1 = (const float*)d_in[3];
    const float* b1 = (const float*)d_in[4];
    const float* W2 = (const float*)d_in[5];
    const float* b2 = (const float*)d_in[6];
    const float* W3 = (const float*)d_in[7];
    const float* b3 = (const float*)d_in[8];
    const float* Wf = (const float*)d_in[9];
    const float* bf = (const float*)d_in[10];

    const int* src = ei;              // edge_index[0] = message sources
    const int* dst = ei + N_EDGES;    // edge_index[1] = aggregation targets

    float* ws   = (float*)d_ws;
    float* dis  = ws;                            // N
    float* g    = dis + N_NODES;                 // N*32 (max)
    float* acc  = g   + (size_t)N_NODES * 32;    // N*32 (max)
    float* O1   = acc + (size_t)N_NODES * 32;    // N*32
    float* O2   = O1  + (size_t)N_NODES * 32;    // N*16
    float* pool = O2  + (size_t)N_NODES * 16;    // 64*8 sums + 64 counts

    hipMemsetAsync(dis,  0, N_NODES * sizeof(float), stream);
    hipMemsetAsync(pool, 0, N_GRAPHS * 9 * sizeof(float), stream);

    const int B = 256;
    count_deg_kernel<<<(N_EDGES + B - 1) / B, B, 0, stream>>>(dst, dis);
    finish_dis_kernel<<<(N_NODES + B - 1) / B, B, 0, stream>>>(dis);

    // Layer 1: 3 -> 32
    lin_kernel<3, 32><<<(N_NODES + B - 1) / B, B, 0, stream>>>(x, W1, dis, g, acc);
    edge_kernel<32><<<(int)(((long long)N_EDGES * 8 + B - 1) / B), B, 0, stream>>>(src, dst, g, acc);
    post_kernel<32><<<(N_NODES * 32 + B - 1) / B, B, 0, stream>>>(acc, dis, b1, O1);

    // Layer 2: 32 -> 16
    lin_kernel<32, 16><<<(N_NODES + B - 1) / B, B, 0, stream>>>(O1, W2, dis, g, acc);
    edge_kernel<16><<<(int)(((long long)N_EDGES * 4 + B - 1) / B), B, 0, stream>>>(src, dst, g, acc);
    post_kernel<16><<<(N_NODES * 16 + B - 1) / B, B, 0, stream>>>(acc, dis, b2, O2);

    // Layer 3: 16 -> 8
    lin_kernel<16, 8><<<(N_NODES + B - 1) / B, B, 0, stream>>>(O2, W3, dis, g, acc);
    edge_kernel<8><<<(int)(((long long)N_EDGES * 2 + B - 1) / B), B, 0, stream>>>(src, dst, g, acc);
    post_kernel<8><<<(N_NODES * 8 + B - 1) / B, B, 0, stream>>>(acc, dis, b3, O1);  // reuse O1

    // Pool + final linear
    pool_kernel<<<(N_NODES + B - 1) / B, B, 0, stream>>>(O1, batch, pool);
    final_kernel<<<1, 256, 0, stream>>>(pool, Wf, bf, (float*)d_out);
}

// Round 2
// 519.040 us; speedup vs baseline: 5.3499x; 5.3499x over previous
//
#include <hip/hip_runtime.h>

constexpr int N_NODES  = 100000;
constexpr int N_EDGES  = 3200000;
constexpr int N_GRAPHS = 64;

// ================= CSR construction =================

__global__ void count_deg_kernel(const int* __restrict__ dst, int* __restrict__ degi) {
    int e = blockIdx.x * blockDim.x + threadIdx.x;
    if (e < N_EDGES) atomicAdd(&degi[dst[e]], 1);
}

__global__ void finish_dis_kernel(const int* __restrict__ degi, float* __restrict__ dis) {
    int i = blockIdx.x * blockDim.x + threadIdx.x;
    if (i < N_NODES) dis[i] = 1.0f / sqrtf((float)degi[i] + 1.0f);  // +1 self loop
}

// exclusive scan of degi -> rowptr, 3-kernel scheme
__global__ void scan1_kernel(const int* __restrict__ degi, int* __restrict__ rowptr,
                             int* __restrict__ bsum) {
    __shared__ int s[256];
    int tid = threadIdx.x;
    int i = blockIdx.x * 256 + tid;
    int v = (i < N_NODES) ? degi[i] : 0;
    s[tid] = v;
    __syncthreads();
    for (int o = 1; o < 256; o <<= 1) {
        int t = (tid >= o) ? s[tid - o] : 0;
        __syncthreads();
        s[tid] += t;
        __syncthreads();
    }
    if (i < N_NODES) rowptr[i] = s[tid] - v;          // block-local exclusive
    if (tid == 255) bsum[blockIdx.x] = s[255];
}

__global__ void scan2_kernel(int* __restrict__ bsum, int nb) {
    __shared__ int s[512];
    int tid = threadIdx.x;
    int v = (tid < nb) ? bsum[tid] : 0;
    s[tid] = v;
    __syncthreads();
    for (int o = 1; o < 512; o <<= 1) {
        int t = (tid >= o) ? s[tid - o] : 0;
        __syncthreads();
        s[tid] += t;
        __syncthreads();
    }
    if (tid < nb) bsum[tid] = s[tid] - v;             // exclusive block offsets
}

__global__ void scan3_kernel(int* __restrict__ rowptr, const int* __restrict__ bsum) {
    int i = blockIdx.x * 256 + threadIdx.x;
    if (i < N_NODES) rowptr[i] += bsum[i >> 8];
    else if (i == N_NODES) rowptr[N_NODES] = N_EDGES;
}

__global__ void fill_kernel(const int* __restrict__ src, const int* __restrict__ dst,
                            const int* __restrict__ rowptr, int* __restrict__ cur,
                            int* __restrict__ csr) {
    int e = blockIdx.x * blockDim.x + threadIdx.x;
    if (e >= N_EDGES) return;
    int d = dst[e];
    int pos = rowptr[d] + atomicAdd(&cur[d], 1);
    csr[pos] = src[e];
}

// ================= per-layer kernels =================

// xs[i,0:3] = x[i,:]*dis[i], xs[i,3] = 0   (aggregate BEFORE W1: 3-dim << 32-dim)
__global__ void pre1_kernel(const float* __restrict__ x, const float* __restrict__ dis,
                            float* __restrict__ xs) {
    int i = blockIdx.x * blockDim.x + threadIdx.x;
    if (i >= N_NODES) return;
    float d = dis[i];
    float4 v;
    v.x = x[(size_t)i * 3 + 0] * d;
    v.y = x[(size_t)i * 3 + 1] * d;
    v.z = x[(size_t)i * 3 + 2] * d;
    v.w = 0.f;
    *reinterpret_cast<float4*>(&xs[(size_t)i * 4]) = v;
}

// group of F lanes per node: acc = in[n] (self) + sum_{e: dst=n} in[src]; epilogue dis/b/relu
template<int F, bool ADD_B, bool RELU>
__global__ void gather_kernel(const float* __restrict__ in, const int* __restrict__ rowptr,
                              const int* __restrict__ csr, const float* __restrict__ dis,
                              const float* __restrict__ b, float* __restrict__ out) {
    constexpr int GPB = 256 / F;
    int tid = threadIdx.x;
    int l = tid & (F - 1);
    int n = blockIdx.x * GPB + (tid / F);
    if (n >= N_NODES) return;
    int beg = rowptr[n], end = rowptr[n + 1];
    float a0 = in[(size_t)n * F + l];   // self loop (already dis[src]-scaled)
    float a1 = 0.f;
    int k = beg;
    for (; k + 1 < end; k += 2) {
        int s0 = csr[k], s1 = csr[k + 1];
        a0 += in[(size_t)s0 * F + l];
        a1 += in[(size_t)s1 * F + l];
    }
    if (k < end) a0 += in[(size_t)csr[k] * F + l];
    float v = (a0 + a1) * dis[n];
    if (ADD_B) v += b[l];
    if (RELU) v = fmaxf(v, 0.f);
    out[(size_t)n * F + l] = v;
}

// h1[i,f] = relu( sum_k m[i,k]*W1[k,f] + b1[f] ), m is 4-padded (k<3)
__global__ void lin1_kernel(const float* __restrict__ m, const float* __restrict__ W1,
                            const float* __restrict__ b1, float* __restrict__ h1) {
    int i = blockIdx.x * blockDim.x + threadIdx.x;
    if (i >= N_NODES) return;
    float4 mv = *reinterpret_cast<const float4*>(&m[(size_t)i * 4]);
#pragma unroll
    for (int f = 0; f < 32; ++f) {
        float s = b1[f];
        s = fmaf(mv.x, W1[0 * 32 + f], s);
        s = fmaf(mv.y, W1[1 * 32 + f], s);
        s = fmaf(mv.z, W1[2 * 32 + f], s);
        h1[(size_t)i * 32 + f] = fmaxf(s, 0.f);
    }
}

// g[i,:FOUT] = (in[i,:FIN] @ W) * dis[i]
template<int FIN, int FOUT>
__global__ void lin_pre_kernel(const float* __restrict__ in, const float* __restrict__ W,
                               const float* __restrict__ dis, float* __restrict__ g) {
    int i = blockIdx.x * blockDim.x + threadIdx.x;
    if (i >= N_NODES) return;
    float xin[FIN];
#pragma unroll
    for (int k = 0; k < FIN; ++k) xin[k] = in[(size_t)i * FIN + k];
    float d = dis[i];
#pragma unroll
    for (int f = 0; f < FOUT; ++f) {
        float s = 0.f;
#pragma unroll
        for (int k = 0; k < FIN; ++k) s = fmaf(xin[k], W[k * FOUT + f], s);
        g[(size_t)i * FOUT + f] = s * d;
    }
}

// ================= pooling + final linear =================

__global__ void pool_kernel(const float* __restrict__ h, const int* __restrict__ batch,
                            float* __restrict__ pool) {
    __shared__ float lsum[N_GRAPHS * 8];
    __shared__ float lcnt[N_GRAPHS];
    int tid = threadIdx.x;
    for (int j = tid; j < N_GRAPHS * 8; j += blockDim.x) lsum[j] = 0.f;
    for (int j = tid; j < N_GRAPHS; j += blockDim.x) lcnt[j] = 0.f;
    __syncthreads();
    int i = blockIdx.x * blockDim.x + tid;
    if (i < N_NODES) {
        int gm = batch[i];
        const float4* hp = reinterpret_cast<const float4*>(&h[(size_t)i * 8]);
        float4 a = hp[0], bq = hp[1];
        atomicAdd(&lsum[gm * 8 + 0], a.x);
        atomicAdd(&lsum[gm * 8 + 1], a.y);
        atomicAdd(&lsum[gm * 8 + 2], a.z);
        atomicAdd(&lsum[gm * 8 + 3], a.w);
        atomicAdd(&lsum[gm * 8 + 4], bq.x);
        atomicAdd(&lsum[gm * 8 + 5], bq.y);
        atomicAdd(&lsum[gm * 8 + 6], bq.z);
        atomicAdd(&lsum[gm * 8 + 7], bq.w);
        atomicAdd(&lcnt[gm], 1.0f);
    }
    __syncthreads();
    for (int idx = tid; idx < N_GRAPHS * 9; idx += blockDim.x) {
        int gm = idx / 9, j = idx % 9;
        if (lcnt[gm] != 0.f) {
            if (j < 8) atomicAdd(&pool[gm * 8 + j], lsum[gm * 8 + j]);
            else       atomicAdd(&pool[512 + gm], lcnt[gm]);
        }
    }
}

__global__ void final_kernel(const float* __restrict__ pool, const float* __restrict__ Wf,
                             const float* __restrict__ bf, float* __restrict__ out) {
    int t = threadIdx.x;
    if (t >= N_GRAPHS * 3) return;
    int gm = t / 3, c = t % 3;
    float cnt = fmaxf(pool[512 + gm], 1.0f);
    float s = 0.f;
#pragma unroll
    for (int f = 0; f < 8; ++f) s = fmaf(pool[gm * 8 + f] / cnt, Wf[f * 3 + c], s);
    out[t] = s + bf[c];
}

// ================= launch =================

extern "C" void kernel_launch(void* const* d_in, const int* in_sizes, int n_in,
                              void* d_out, int out_size, void* d_ws, size_t ws_size,
                              hipStream_t stream) {
    const float* x     = (const float*)d_in[0];
    const int*   ei    = (const int*)d_in[1];
    const int*   batch = (const int*)d_in[2];
    const float* W1 = (const float*)d_in[3];
    const float* b1 = (const float*)d_in[4];
    const float* W2 = (const float*)d_in[5];
    const float* b2 = (const float*)d_in[6];
    const float* W3 = (const float*)d_in[7];
    const float* b3 = (const float*)d_in[8];
    const float* Wf = (const float*)d_in[9];
    const float* bf = (const float*)d_in[10];

    const int* src = ei;              // edge_index[0] = message sources
    const int* dst = ei + N_EDGES;    // edge_index[1] = aggregation targets

    const int N = N_NODES, E = N_EDGES;

    // workspace layout (degi doubles as cursor after rowptr built)
    int*   degi   = (int*)d_ws;                        // N  (later: cur)
    int*   rowptr = degi + N;                          // N+1
    int*   bsum   = rowptr + (N + 1);                  // 512
    int*   csr    = bsum + 512;                        // E
    float* dis    = (float*)(csr + E);                 // N
    float* xs     = dis + N;                           // 4N  } 8N region,
    float* m      = xs + (size_t)4 * N;                // 4N  } reused as h3
    float* h1     = m + (size_t)4 * N;                 // 32N
    float* g      = h1 + (size_t)32 * N;               // 16N
    float* h2     = g + (size_t)16 * N;                // 16N
    float* pool   = h2 + (size_t)16 * N;               // 576
    float* h3     = xs;                                // alias (8N)

    const int B = 256;
    const int NB_N  = (N + B - 1) / B;        // 391
    const int NB_E  = (E + B - 1) / B;        // 12500
    const int NB_N1 = (N + 1 + B - 1) / B;    // covers i==N

    hipMemsetAsync(degi, 0, N * sizeof(int), stream);
    hipMemsetAsync(pool, 0, N_GRAPHS * 9 * sizeof(float), stream);

    // CSR build + normalization
    count_deg_kernel<<<NB_E, B, 0, stream>>>(dst, degi);
    finish_dis_kernel<<<NB_N, B, 0, stream>>>(degi, dis);
    scan1_kernel<<<NB_N, B, 0, stream>>>(degi, rowptr, bsum);
    scan2_kernel<<<1, 512, 0, stream>>>(bsum, NB_N);
    scan3_kernel<<<NB_N1, B, 0, stream>>>(rowptr, bsum);
    hipMemsetAsync(degi, 0, N * sizeof(int), stream);   // degi -> cursor
    fill_kernel<<<NB_E, B, 0, stream>>>(src, dst, rowptr, degi, csr);

    // Layer 1: aggregate in 3(4)-dim input space, then 4->32 linear (+b,relu)
    pre1_kernel<<<NB_N, B, 0, stream>>>(x, dis, xs);
    gather_kernel<4, false, false><<<(N + 63) / 64, B, 0, stream>>>(xs, rowptr, csr, dis, b1, m);
    lin1_kernel<<<NB_N, B, 0, stream>>>(m, W1, b1, h1);

    // Layer 2: 32->16 linear (*dis), gather 16, (+b2, relu)
    lin_pre_kernel<32, 16><<<NB_N, B, 0, stream>>>(h1, W2, dis, g);
    gather_kernel<16, true, true><<<(N + 15) / 16, B, 0, stream>>>(g, rowptr, csr, dis, b2, h2);

    // Layer 3: 16->8 linear (*dis), gather 8, (+b3, relu)
    lin_pre_kernel<16, 8><<<NB_N, B, 0, stream>>>(h2, W3, dis, g);
    gather_kernel<8, true, true><<<(N + 31) / 32, B, 0, stream>>>(g, rowptr, csr, dis, b3, h3);

    // Pool + final linear
    pool_kernel<<<NB_N, B, 0, stream>>>(h3, batch, pool);
    final_kernel<<<1, 256, 0, stream>>>(pool, Wf, bf, (float*)d_out);
}

// Round 3
// 395.034 us; speedup vs baseline: 7.0293x; 1.3139x over previous
//
#include <hip/hip_runtime.h>

constexpr int N_NODES  = 100000;
constexpr int N_EDGES  = 3200000;
constexpr int N_GRAPHS = 64;

// ================= CSR construction =================

// one atomic pass: degree count AND per-edge rank within its destination row
__global__ void rank_kernel(const int* __restrict__ dst, int* __restrict__ degi,
                            int* __restrict__ rank) {
    int e = blockIdx.x * blockDim.x + threadIdx.x;
    if (e < N_EDGES) rank[e] = atomicAdd(&degi[dst[e]], 1);
}

__global__ void finish_dis_kernel(const int* __restrict__ degi, float* __restrict__ dis) {
    int i = blockIdx.x * blockDim.x + threadIdx.x;
    if (i < N_NODES) dis[i] = 1.0f / sqrtf((float)degi[i] + 1.0f);  // +1 self loop
}

// exclusive scan of degi -> rowptr, 3-kernel scheme
__global__ void scan1_kernel(const int* __restrict__ degi, int* __restrict__ rowptr,
                             int* __restrict__ bsum) {
    __shared__ int s[256];
    int tid = threadIdx.x;
    int i = blockIdx.x * 256 + tid;
    int v = (i < N_NODES) ? degi[i] : 0;
    s[tid] = v;
    __syncthreads();
    for (int o = 1; o < 256; o <<= 1) {
        int t = (tid >= o) ? s[tid - o] : 0;
        __syncthreads();
        s[tid] += t;
        __syncthreads();
    }
    if (i < N_NODES) rowptr[i] = s[tid] - v;          // block-local exclusive
    if (tid == 255) bsum[blockIdx.x] = s[255];
}

__global__ void scan2_kernel(int* __restrict__ bsum, int nb) {
    __shared__ int s[512];
    int tid = threadIdx.x;
    int v = (tid < nb) ? bsum[tid] : 0;
    s[tid] = v;
    __syncthreads();
    for (int o = 1; o < 512; o <<= 1) {
        int t = (tid >= o) ? s[tid - o] : 0;
        __syncthreads();
        s[tid] += t;
        __syncthreads();
    }
    if (tid < nb) bsum[tid] = s[tid] - v;             // exclusive block offsets
}

__global__ void scan3_kernel(int* __restrict__ rowptr, const int* __restrict__ bsum) {
    int i = blockIdx.x * 256 + threadIdx.x;
    if (i < N_NODES) rowptr[i] += bsum[i >> 8];
    else if (i == N_NODES) rowptr[N_NODES] = N_EDGES;
}

// non-atomic scatter: slot is fully determined by rowptr + precomputed rank
__global__ void fill_kernel(const int* __restrict__ src, const int* __restrict__ dst,
                            const int* __restrict__ rowptr, const int* __restrict__ rank,
                            int* __restrict__ csr) {
    int e = blockIdx.x * blockDim.x + threadIdx.x;
    if (e >= N_EDGES) return;
    int pos = rowptr[dst[e]] + rank[e];
    __builtin_nontemporal_store(src[e], &csr[pos]);   // bypass L2: no line ping-pong
}

// ================= per-layer kernels =================

// xs[i,0:3] = x[i,:]*dis[i], xs[i,3] = 0   (aggregate BEFORE W1: 3-dim << 32-dim)
__global__ void pre1_kernel(const float* __restrict__ x, const float* __restrict__ dis,
                            float* __restrict__ xs) {
    int i = blockIdx.x * blockDim.x + threadIdx.x;
    if (i >= N_NODES) return;
    float d = dis[i];
    float4 v;
    v.x = x[(size_t)i * 3 + 0] * d;
    v.y = x[(size_t)i * 3 + 1] * d;
    v.z = x[(size_t)i * 3 + 2] * d;
    v.w = 0.f;
    *reinterpret_cast<float4*>(&xs[(size_t)i * 4]) = v;
}

// group of F lanes per node: acc = in[n] (self) + sum_{e: dst=n} in[src]; epilogue dis/b/relu
template<int F, bool ADD_B, bool RELU>
__global__ void gather_kernel(const float* __restrict__ in, const int* __restrict__ rowptr,
                              const int* __restrict__ csr, const float* __restrict__ dis,
                              const float* __restrict__ b, float* __restrict__ out) {
    constexpr int GPB = 256 / F;
    int tid = threadIdx.x;
    int l = tid & (F - 1);
    int n = blockIdx.x * GPB + (tid / F);
    if (n >= N_NODES) return;
    int beg = rowptr[n], end = rowptr[n + 1];
    float a0 = in[(size_t)n * F + l];   // self loop (already dis[src]-scaled)
    float a1 = 0.f, a2 = 0.f, a3 = 0.f;
    int k = beg;
    for (; k + 3 < end; k += 4) {
        int s0 = csr[k], s1 = csr[k + 1], s2 = csr[k + 2], s3 = csr[k + 3];
        a0 += in[(size_t)s0 * F + l];
        a1 += in[(size_t)s1 * F + l];
        a2 += in[(size_t)s2 * F + l];
        a3 += in[(size_t)s3 * F + l];
    }
    for (; k < end; ++k) a0 += in[(size_t)csr[k] * F + l];
    float v = ((a0 + a1) + (a2 + a3)) * dis[n];
    if (ADD_B) v += b[l];
    if (RELU) v = fmaxf(v, 0.f);
    out[(size_t)n * F + l] = v;
}

// h1[i,f] = relu( sum_k m[i,k]*W1[k,f] + b1[f] ), m is 4-padded (k<3)
__global__ void lin1_kernel(const float* __restrict__ m, const float* __restrict__ W1,
                            const float* __restrict__ b1, float* __restrict__ h1) {
    int i = blockIdx.x * blockDim.x + threadIdx.x;
    if (i >= N_NODES) return;
    float4 mv = *reinterpret_cast<const float4*>(&m[(size_t)i * 4]);
#pragma unroll
    for (int f = 0; f < 32; ++f) {
        float s = b1[f];
        s = fmaf(mv.x, W1[0 * 32 + f], s);
        s = fmaf(mv.y, W1[1 * 32 + f], s);
        s = fmaf(mv.z, W1[2 * 32 + f], s);
        h1[(size_t)i * 32 + f] = fmaxf(s, 0.f);
    }
}

// g[i,:FOUT] = (in[i,:FIN] @ W) * dis[i]
template<int FIN, int FOUT>
__global__ void lin_pre_kernel(const float* __restrict__ in, const float* __restrict__ W,
                               const float* __restrict__ dis, float* __restrict__ g) {
    int i = blockIdx.x * blockDim.x + threadIdx.x;
    if (i >= N_NODES) return;
    float xin[FIN];
#pragma unroll
    for (int k = 0; k < FIN; ++k) xin[k] = in[(size_t)i * FIN + k];
    float d = dis[i];
#pragma unroll
    for (int f = 0; f < FOUT; ++f) {
        float s = 0.f;
#pragma unroll
        for (int k = 0; k < FIN; ++k) s = fmaf(xin[k], W[k * FOUT + f], s);
        g[(size_t)i * FOUT + f] = s * d;
    }
}

// ================= pooling + final linear =================

__global__ void pool_kernel(const float* __restrict__ h, const int* __restrict__ batch,
                            float* __restrict__ pool) {
    __shared__ float lsum[N_GRAPHS * 8];
    __shared__ float lcnt[N_GRAPHS];
    int tid = threadIdx.x;
    for (int j = tid; j < N_GRAPHS * 8; j += blockDim.x) lsum[j] = 0.f;
    for (int j = tid; j < N_GRAPHS; j += blockDim.x) lcnt[j] = 0.f;
    __syncthreads();
    int i = blockIdx.x * blockDim.x + tid;
    if (i < N_NODES) {
        int gm = batch[i];
        const float4* hp = reinterpret_cast<const float4*>(&h[(size_t)i * 8]);
        float4 a = hp[0], bq = hp[1];
        atomicAdd(&lsum[gm * 8 + 0], a.x);
        atomicAdd(&lsum[gm * 8 + 1], a.y);
        atomicAdd(&lsum[gm * 8 + 2], a.z);
        atomicAdd(&lsum[gm * 8 + 3], a.w);
        atomicAdd(&lsum[gm * 8 + 4], bq.x);
        atomicAdd(&lsum[gm * 8 + 5], bq.y);
        atomicAdd(&lsum[gm * 8 + 6], bq.z);
        atomicAdd(&lsum[gm * 8 + 7], bq.w);
        atomicAdd(&lcnt[gm], 1.0f);
    }
    __syncthreads();
    for (int idx = tid; idx < N_GRAPHS * 9; idx += blockDim.x) {
        int gm = idx / 9, j = idx % 9;
        if (lcnt[gm] != 0.f) {
            if (j < 8) atomicAdd(&pool[gm * 8 + j], lsum[gm * 8 + j]);
            else       atomicAdd(&pool[512 + gm], lcnt[gm]);
        }
    }
}

__global__ void final_kernel(const float* __restrict__ pool, const float* __restrict__ Wf,
                             const float* __restrict__ bf, float* __restrict__ out) {
    int t = threadIdx.x;
    if (t >= N_GRAPHS * 3) return;
    int gm = t / 3, c = t % 3;
    float cnt = fmaxf(pool[512 + gm], 1.0f);
    float s = 0.f;
#pragma unroll
    for (int f = 0; f < 8; ++f) s = fmaf(pool[gm * 8 + f] / cnt, Wf[f * 3 + c], s);
    out[t] = s + bf[c];
}

// ================= launch =================

extern "C" void kernel_launch(void* const* d_in, const int* in_sizes, int n_in,
                              void* d_out, int out_size, void* d_ws, size_t ws_size,
                              hipStream_t stream) {
    const float* x     = (const float*)d_in[0];
    const int*   ei    = (const int*)d_in[1];
    const int*   batch = (const int*)d_in[2];
    const float* W1 = (const float*)d_in[3];
    const float* b1 = (const float*)d_in[4];
    const float* W2 = (const float*)d_in[5];
    const float* b2 = (const float*)d_in[6];
    const float* W3 = (const float*)d_in[7];
    const float* b3 = (const float*)d_in[8];
    const float* Wf = (const float*)d_in[9];
    const float* bf = (const float*)d_in[10];

    const int* src = ei;              // edge_index[0] = message sources
    const int* dst = ei + N_EDGES;    // edge_index[1] = aggregation targets

    const int N = N_NODES, E = N_EDGES;

    // workspace layout
    int*   degi   = (int*)d_ws;                        // N
    int*   rowptr = degi + N;                          // N+1
    int*   bsum   = rowptr + (N + 1);                  // 512
    int*   csr    = bsum + 512;                        // E
    float* dis    = (float*)(csr + E);                 // N
    float* xs     = dis + N;                           // 4N  } 8N region,
    float* m      = xs + (size_t)4 * N;                // 4N  } reused as h3
    float* h1     = m + (size_t)4 * N;                 // 32N
    float* g      = h1 + (size_t)32 * N;               // 16N
    float* h2     = g + (size_t)16 * N;                // 16N
    float* pool   = h2 + (size_t)16 * N;               // 576
    float* h3     = xs;                                // alias (8N)
    int*   rank   = (int*)h1;                          // alias: E ints == 32N floats? (E=3.2M, 32N=3.2M) ✓
                                                       // rank is dead before h1 is written

    const int B = 256;
    const int NB_N  = (N + B - 1) / B;        // 391
    const int NB_E  = (E + B - 1) / B;        // 12500
    const int NB_N1 = (N + 1 + B - 1) / B;    // covers i==N

    hipMemsetAsync(degi, 0, N * sizeof(int), stream);
    hipMemsetAsync(pool, 0, N_GRAPHS * 9 * sizeof(float), stream);

    // CSR build + normalization (single atomic pass)
    rank_kernel<<<NB_E, B, 0, stream>>>(dst, degi, rank);
    finish_dis_kernel<<<NB_N, B, 0, stream>>>(degi, dis);
    scan1_kernel<<<NB_N, B, 0, stream>>>(degi, rowptr, bsum);
    scan2_kernel<<<1, 512, 0, stream>>>(bsum, NB_N);
    scan3_kernel<<<NB_N1, B, 0, stream>>>(rowptr, bsum);
    fill_kernel<<<NB_E, B, 0, stream>>>(src, dst, rowptr, rank, csr);

    // Layer 1: aggregate in 3(4)-dim input space, then 4->32 linear (+b,relu)
    pre1_kernel<<<NB_N, B, 0, stream>>>(x, dis, xs);
    gather_kernel<4, false, false><<<(N + 63) / 64, B, 0, stream>>>(xs, rowptr, csr, dis, b1, m);
    lin1_kernel<<<NB_N, B, 0, stream>>>(m, W1, b1, h1);

    // Layer 2: 32->16 linear (*dis), gather 16, (+b2, relu)
    lin_pre_kernel<32, 16><<<NB_N, B, 0, stream>>>(h1, W2, dis, g);
    gather_kernel<16, true, true><<<(N + 15) / 16, B, 0, stream>>>(g, rowptr, csr, dis, b2, h2);

    // Layer 3: 16->8 linear (*dis), gather 8, (+b3, relu)
    lin_pre_kernel<16, 8><<<NB_N, B, 0, stream>>>(h2, W3, dis, g);
    gather_kernel<8, true, true><<<(N + 31) / 32, B, 0, stream>>>(g, rowptr, csr, dis, b3, h3);

    // Pool + final linear
    pool_kernel<<<NB_N, B, 0, stream>>>(h3, batch, pool);
    final_kernel<<<1, 256, 0, stream>>>(pool, Wf, bf, (float*)d_out);
}

// Round 4
// 220.565 us; speedup vs baseline: 12.5896x; 1.7910x over previous
//
#include <hip/hip_runtime.h>

constexpr int N_NODES  = 100000;
constexpr int N_EDGES  = 3200000;
constexpr int N_GRAPHS = 64;

constexpr int BSHIFT  = 8;                               // 256 nodes per bin
constexpr int NBINS   = (N_NODES + 255) >> BSHIFT;       // 391
constexpr int BIN_CAP = 9216;                            // mean 8192, +11 sigma
constexpr int EPB     = 8192;                            // edges per bin_kernel block
constexpr int NB_BIN  = (N_EDGES + EPB - 1) / EPB;       // 391

// ================= counting-sort CSR build =================

// Pass 1: bucket edges by dst>>8. Per-edge atomics are LDS-only; one global
// atomic per (block,bin) reserves space in the bin's fixed-stride region.
__global__ void bin_kernel(const int* __restrict__ src, const int* __restrict__ dst,
                           int* __restrict__ bin_cur, int2* __restrict__ binned) {
    __shared__ int hist[NBINS];
    __shared__ int base[NBINS];
    int tid = threadIdx.x;
    int e0 = blockIdx.x * EPB;
    int e1 = min(e0 + EPB, N_EDGES);
    for (int i = tid; i < NBINS; i += 256) hist[i] = 0;
    __syncthreads();
    for (int e = e0 + tid; e < e1; e += 256) atomicAdd(&hist[dst[e] >> BSHIFT], 1);
    __syncthreads();
    for (int i = tid; i < NBINS; i += 256) {
        int h = hist[i];
        base[i] = h ? atomicAdd(&bin_cur[i], h) : 0;
    }
    __syncthreads();
    for (int i = tid; i < NBINS; i += 256) hist[i] = 0;   // reset for ranking
    __syncthreads();
    for (int e = e0 + tid; e < e1; e += 256) {
        int d = dst[e];
        int b = d >> BSHIFT;
        int r = base[b] + atomicAdd(&hist[b], 1);
        if (r < BIN_CAP) binned[(size_t)b * BIN_CAP + r] = make_int2(src[e], d);
    }
}

// exclusive scan of bin sizes -> bin_base (391 values, one block)
__global__ void binscan_kernel(const int* __restrict__ bin_cur, int* __restrict__ bin_base,
                               int* __restrict__ rowptr) {
    __shared__ int s[512];
    int t = threadIdx.x;
    int v = (t < NBINS) ? bin_cur[t] : 0;
    s[t] = v;
    __syncthreads();
    for (int o = 1; o < 512; o <<= 1) {
        int x = (t >= o) ? s[t - o] : 0;
        __syncthreads();
        s[t] += x;
        __syncthreads();
    }
    if (t < NBINS) bin_base[t] = s[t] - v;
    if (t == 0) rowptr[N_NODES] = N_EDGES;
}

// Pass 2: one block per bin. LDS count -> dis + rowptr; LDS rank -> csr.
__global__ void csrbuild_kernel(const int2* __restrict__ binned, const int* __restrict__ bin_cur,
                                const int* __restrict__ bin_base, int* __restrict__ rowptr,
                                float* __restrict__ dis, int* __restrict__ csr) {
    __shared__ int cnt[256];
    __shared__ int lofs[256];
    __shared__ int s[256];
    int b = blockIdx.x;
    int t = threadIdx.x;
    int n = (b << BSHIFT) + t;
    int size  = min(bin_cur[b], BIN_CAP);
    int gbase = bin_base[b];
    const int2* bp = binned + (size_t)b * BIN_CAP;
    cnt[t] = 0;
    __syncthreads();
    for (int i = t; i < size; i += 256) atomicAdd(&cnt[bp[i].y & 255], 1);
    __syncthreads();
    int deg = cnt[t];
    if (n < N_NODES) dis[n] = 1.0f / sqrtf((float)deg + 1.0f);  // +1 self loop
    s[t] = deg;
    __syncthreads();
    for (int o = 1; o < 256; o <<= 1) {
        int x = (t >= o) ? s[t - o] : 0;
        __syncthreads();
        s[t] += x;
        __syncthreads();
    }
    int excl = s[t] - deg;
    if (n < N_NODES) rowptr[n] = gbase + excl;
    lofs[t] = excl;
    cnt[t] = 0;                                   // reset for ranking
    __syncthreads();
    for (int i = t; i < size; i += 256) {
        int2 ed = bp[i];
        int ln = ed.y & 255;
        int r = atomicAdd(&cnt[ln], 1);
        csr[gbase + lofs[ln] + r] = ed.x;         // scatter within ~32KB bin segment
    }
}

// ================= per-layer kernels =================

// xs[i,0:3] = x[i,:]*dis[i], xs[i,3] = 0   (aggregate BEFORE W1: 3-dim << 32-dim)
__global__ void pre1_kernel(const float* __restrict__ x, const float* __restrict__ dis,
                            float* __restrict__ xs) {
    int i = blockIdx.x * blockDim.x + threadIdx.x;
    if (i >= N_NODES) return;
    float d = dis[i];
    float4 v;
    v.x = x[(size_t)i * 3 + 0] * d;
    v.y = x[(size_t)i * 3 + 1] * d;
    v.z = x[(size_t)i * 3 + 2] * d;
    v.w = 0.f;
    *reinterpret_cast<float4*>(&xs[(size_t)i * 4]) = v;
}

// group of F lanes per node: acc = in[n] (self) + sum_{e: dst=n} in[src]; epilogue dis/b/relu
template<int F, bool ADD_B, bool RELU>
__global__ void gather_kernel(const float* __restrict__ in, const int* __restrict__ rowptr,
                              const int* __restrict__ csr, const float* __restrict__ dis,
                              const float* __restrict__ b, float* __restrict__ out) {
    constexpr int GPB = 256 / F;
    int tid = threadIdx.x;
    int l = tid & (F - 1);
    int n = blockIdx.x * GPB + (tid / F);
    if (n >= N_NODES) return;
    int beg = rowptr[n], end = rowptr[n + 1];
    float a0 = in[(size_t)n * F + l];   // self loop (already dis[src]-scaled)
    float a1 = 0.f, a2 = 0.f, a3 = 0.f;
    int k = beg;
    for (; k + 3 < end; k += 4) {
        int s0 = csr[k], s1 = csr[k + 1], s2 = csr[k + 2], s3 = csr[k + 3];
        a0 += in[(size_t)s0 * F + l];
        a1 += in[(size_t)s1 * F + l];
        a2 += in[(size_t)s2 * F + l];
        a3 += in[(size_t)s3 * F + l];
    }
    for (; k < end; ++k) a0 += in[(size_t)csr[k] * F + l];
    float v = ((a0 + a1) + (a2 + a3)) * dis[n];
    if (ADD_B) v += b[l];
    if (RELU) v = fmaxf(v, 0.f);
    out[(size_t)n * F + l] = v;
}

// h1[i,f] = relu( sum_k m[i,k]*W1[k,f] + b1[f] ), m is 4-padded (k<3)
__global__ void lin1_kernel(const float* __restrict__ m, const float* __restrict__ W1,
                            const float* __restrict__ b1, float* __restrict__ h1) {
    int i = blockIdx.x * blockDim.x + threadIdx.x;
    if (i >= N_NODES) return;
    float4 mv = *reinterpret_cast<const float4*>(&m[(size_t)i * 4]);
#pragma unroll
    for (int f = 0; f < 32; ++f) {
        float s = b1[f];
        s = fmaf(mv.x, W1[0 * 32 + f], s);
        s = fmaf(mv.y, W1[1 * 32 + f], s);
        s = fmaf(mv.z, W1[2 * 32 + f], s);
        h1[(size_t)i * 32 + f] = fmaxf(s, 0.f);
    }
}

// g[i,:FOUT] = (in[i,:FIN] @ W) * dis[i]
template<int FIN, int FOUT>
__global__ void lin_pre_kernel(const float* __restrict__ in, const float* __restrict__ W,
                               const float* __restrict__ dis, float* __restrict__ g) {
    int i = blockIdx.x * blockDim.x + threadIdx.x;
    if (i >= N_NODES) return;
    float xin[FIN];
#pragma unroll
    for (int k = 0; k < FIN; ++k) xin[k] = in[(size_t)i * FIN + k];
    float d = dis[i];
#pragma unroll
    for (int f = 0; f < FOUT; ++f) {
        float s = 0.f;
#pragma unroll
        for (int k = 0; k < FIN; ++k) s = fmaf(xin[k], W[k * FOUT + f], s);
        g[(size_t)i * FOUT + f] = s * d;
    }
}

// ================= pooling + final linear =================

__global__ void pool_kernel(const float* __restrict__ h, const int* __restrict__ batch,
                            float* __restrict__ pool) {
    __shared__ float lsum[N_GRAPHS * 8];
    __shared__ float lcnt[N_GRAPHS];
    int tid = threadIdx.x;
    for (int j = tid; j < N_GRAPHS * 8; j += blockDim.x) lsum[j] = 0.f;
    for (int j = tid; j < N_GRAPHS; j += blockDim.x) lcnt[j] = 0.f;
    __syncthreads();
    int i = blockIdx.x * blockDim.x + tid;
    if (i < N_NODES) {
        int gm = batch[i];
        const float4* hp = reinterpret_cast<const float4*>(&h[(size_t)i * 8]);
        float4 a = hp[0], bq = hp[1];
        atomicAdd(&lsum[gm * 8 + 0], a.x);
        atomicAdd(&lsum[gm * 8 + 1], a.y);
        atomicAdd(&lsum[gm * 8 + 2], a.z);
        atomicAdd(&lsum[gm * 8 + 3], a.w);
        atomicAdd(&lsum[gm * 8 + 4], bq.x);
        atomicAdd(&lsum[gm * 8 + 5], bq.y);
        atomicAdd(&lsum[gm * 8 + 6], bq.z);
        atomicAdd(&lsum[gm * 8 + 7], bq.w);
        atomicAdd(&lcnt[gm], 1.0f);
    }
    __syncthreads();
    for (int idx = tid; idx < N_GRAPHS * 9; idx += blockDim.x) {
        int gm = idx / 9, j = idx % 9;
        if (lcnt[gm] != 0.f) {
            if (j < 8) atomicAdd(&pool[gm * 8 + j], lsum[gm * 8 + j]);
            else       atomicAdd(&pool[512 + gm], lcnt[gm]);
        }
    }
}

__global__ void final_kernel(const float* __restrict__ pool, const float* __restrict__ Wf,
                             const float* __restrict__ bf, float* __restrict__ out) {
    int t = threadIdx.x;
    if (t >= N_GRAPHS * 3) return;
    int gm = t / 3, c = t % 3;
    float cnt = fmaxf(pool[512 + gm], 1.0f);
    float s = 0.f;
#pragma unroll
    for (int f = 0; f < 8; ++f) s = fmaf(pool[gm * 8 + f] / cnt, Wf[f * 3 + c], s);
    out[t] = s + bf[c];
}

// ================= launch =================

extern "C" void kernel_launch(void* const* d_in, const int* in_sizes, int n_in,
                              void* d_out, int out_size, void* d_ws, size_t ws_size,
                              hipStream_t stream) {
    const float* x     = (const float*)d_in[0];
    const int*   ei    = (const int*)d_in[1];
    const int*   batch = (const int*)d_in[2];
    const float* W1 = (const float*)d_in[3];
    const float* b1 = (const float*)d_in[4];
    const float* W2 = (const float*)d_in[5];
    const float* b2 = (const float*)d_in[6];
    const float* W3 = (const float*)d_in[7];
    const float* b3 = (const float*)d_in[8];
    const float* Wf = (const float*)d_in[9];
    const float* bf = (const float*)d_in[10];

    const int* src = ei;              // edge_index[0] = message sources
    const int* dst = ei + N_EDGES;    // edge_index[1] = aggregation targets

    const int N = N_NODES, E = N_EDGES;

    // workspace layout (ints unless noted); binned region aliases activations
    int*   bin_cur  = (int*)d_ws;                         // NBINS
    int*   bin_base = bin_cur + NBINS;                    // NBINS
    int*   rowptr   = bin_base + NBINS;                   // N+2 (pad keeps binned 8B-aligned)
    float* dis      = (float*)(rowptr + N + 2);           // N
    int*   csr      = (int*)(dis + N);                    // E
    int2*  binned   = (int2*)(csr + E);                   // NBINS*BIN_CAP int2 (28.8MB)
    float* xs       = (float*)binned;                     // alias: 4N   } activations live
    float* m        = xs + (size_t)4 * N;                 // 4N          } only after csr
    float* h1       = m + (size_t)4 * N;                  // 32N         } is built
    float* g        = h1 + (size_t)32 * N;                // 16N
    float* h2       = g + (size_t)16 * N;                 // 16N
    float* pool     = (float*)(binned + (size_t)NBINS * BIN_CAP);  // 576
    float* h3       = xs;                                 // alias (8N), free at layer 3

    const int B = 256;
    const int NB_N = (N + B - 1) / B;

    hipMemsetAsync(bin_cur, 0, NBINS * sizeof(int), stream);
    hipMemsetAsync(pool, 0, N_GRAPHS * 9 * sizeof(float), stream);

    // CSR build: bucket sort (LDS atomics) -> bin scan -> per-bin CSR + dis + rowptr
    bin_kernel<<<NB_BIN, B, 0, stream>>>(src, dst, bin_cur, binned);
    binscan_kernel<<<1, 512, 0, stream>>>(bin_cur, bin_base, rowptr);
    csrbuild_kernel<<<NBINS, B, 0, stream>>>(binned, bin_cur, bin_base, rowptr, dis, csr);

    // Layer 1: aggregate in 3(4)-dim input space, then 4->32 linear (+b,relu)
    pre1_kernel<<<NB_N, B, 0, stream>>>(x, dis, xs);
    gather_kernel<4, false, false><<<(N + 63) / 64, B, 0, stream>>>(xs, rowptr, csr, dis, b1, m);
    lin1_kernel<<<NB_N, B, 0, stream>>>(m, W1, b1, h1);

    // Layer 2: 32->16 linear (*dis), gather 16, (+b2, relu)
    lin_pre_kernel<32, 16><<<NB_N, B, 0, stream>>>(h1, W2, dis, g);
    gather_kernel<16, true, true><<<(N + 15) / 16, B, 0, stream>>>(g, rowptr, csr, dis, b2, h2);

    // Layer 3: 16->8 linear (*dis), gather 8, (+b3, relu)
    lin_pre_kernel<16, 8><<<NB_N, B, 0, stream>>>(h2, W3, dis, g);
    gather_kernel<8, true, true><<<(N + 31) / 32, B, 0, stream>>>(g, rowptr, csr, dis, b3, h3);

    // Pool + final linear
    pool_kernel<<<NB_N, B, 0, stream>>>(h3, batch, pool);
    final_kernel<<<1, 256, 0, stream>>>(pool, Wf, bf, (float*)d_out);
}

// Round 5
// 202.903 us; speedup vs baseline: 13.6855x; 1.0870x over previous
//
#include <hip/hip_runtime.h>

constexpr int N_NODES  = 100000;
constexpr int N_EDGES  = 3200000;
constexpr int N_GRAPHS = 64;

constexpr int BSHIFT  = 8;                               // 256 nodes per bin
constexpr int NBINS   = (N_NODES + 255) >> BSHIFT;       // 391
constexpr int BIN_CAP = 9216;                            // mean 8192, +11 sigma
constexpr int EPB     = 8192;                            // edges per bin_kernel block
constexpr int NB_BIN  = (N_EDGES + EPB - 1) / EPB;       // 391

// ================= counting-sort CSR build =================

// Pass 1: bucket edges by dst>>8. Per-edge atomics are LDS-only; one global
// atomic per (block,bin) reserves space in the bin's fixed-stride region.
// 1024 threads/block: 16 waves resident per block for latency hiding.
__global__ __launch_bounds__(1024) void bin_kernel(
        const int* __restrict__ src, const int* __restrict__ dst,
        int* __restrict__ bin_cur, int2* __restrict__ binned) {
    __shared__ int hist[NBINS];
    __shared__ int base[NBINS];
    int tid = threadIdx.x;
    int e0 = blockIdx.x * EPB;
    int e1 = min(e0 + EPB, N_EDGES);
    for (int i = tid; i < NBINS; i += 1024) hist[i] = 0;
    __syncthreads();
    for (int e = e0 + tid; e < e1; e += 1024) atomicAdd(&hist[dst[e] >> BSHIFT], 1);
    __syncthreads();
    for (int i = tid; i < NBINS; i += 1024) {
        int h = hist[i];
        base[i] = h ? atomicAdd(&bin_cur[i], h) : 0;
    }
    __syncthreads();
    for (int i = tid; i < NBINS; i += 1024) hist[i] = 0;   // reset for ranking
    __syncthreads();
    for (int e = e0 + tid; e < e1; e += 1024) {
        int d = dst[e];
        int b = d >> BSHIFT;
        int r = base[b] + atomicAdd(&hist[b], 1);
        if (r < BIN_CAP) binned[(size_t)b * BIN_CAP + r] = make_int2(src[e], d);
    }
}

// exclusive scan of bin sizes -> bin_base (391 values, one block)
__global__ void binscan_kernel(const int* __restrict__ bin_cur, int* __restrict__ bin_base,
                               int* __restrict__ rowptr) {
    __shared__ int s[512];
    int t = threadIdx.x;
    int v = (t < NBINS) ? bin_cur[t] : 0;
    s[t] = v;
    __syncthreads();
    for (int o = 1; o < 512; o <<= 1) {
        int x = (t >= o) ? s[t - o] : 0;
        __syncthreads();
        s[t] += x;
        __syncthreads();
    }
    if (t < NBINS) bin_base[t] = s[t] - v;
    if (t == 0) rowptr[N_NODES] = N_EDGES;
}

// Pass 2: one block per bin, 1024 threads. LDS count -> dis + rowptr (scan by
// first 256 lanes); LDS rank -> csr scatter within the bin's ~32KB segment.
__global__ __launch_bounds__(1024) void csrbuild_kernel(
        const int2* __restrict__ binned, const int* __restrict__ bin_cur,
        const int* __restrict__ bin_base, int* __restrict__ rowptr,
        float* __restrict__ dis, int* __restrict__ csr) {
    __shared__ int cnt[256];
    __shared__ int lofs[256];
    __shared__ int s[256];
    int b = blockIdx.x;
    int t = threadIdx.x;
    int size  = min(bin_cur[b], BIN_CAP);
    int gbase = bin_base[b];
    const int2* bp = binned + (size_t)b * BIN_CAP;
    if (t < 256) cnt[t] = 0;
    __syncthreads();
    for (int i = t; i < size; i += 1024) atomicAdd(&cnt[bp[i].y & 255], 1);
    __syncthreads();
    if (t < 256) {
        int n = (b << BSHIFT) + t;
        int deg = cnt[t];
        if (n < N_NODES) dis[n] = 1.0f / sqrtf((float)deg + 1.0f);  // +1 self loop
        s[t] = deg;
    }
    __syncthreads();
    for (int o = 1; o < 256; o <<= 1) {
        int x = 0;
        if (t < 256 && t >= o) x = s[t - o];
        __syncthreads();
        if (t < 256) s[t] += x;
        __syncthreads();
    }
    if (t < 256) {
        int n = (b << BSHIFT) + t;
        int deg = cnt[t];
        int excl = s[t] - deg;
        if (n < N_NODES) rowptr[n] = gbase + excl;
        lofs[t] = excl;
        cnt[t] = 0;                                   // reset for ranking
    }
    __syncthreads();
    for (int i = t; i < size; i += 1024) {
        int2 ed = bp[i];
        int ln = ed.y & 255;
        int r = atomicAdd(&cnt[ln], 1);
        csr[gbase + lofs[ln] + r] = ed.x;
    }
}

// ================= per-layer kernels =================

// xs[i,0:3] = x[i,:]*dis[i], xs[i,3] = 0   (aggregate BEFORE W1: 3-dim << 32-dim)
__global__ void pre1_kernel(const float* __restrict__ x, const float* __restrict__ dis,
                            float* __restrict__ xs) {
    int i = blockIdx.x * blockDim.x + threadIdx.x;
    if (i >= N_NODES) return;
    float d = dis[i];
    float4 v;
    v.x = x[(size_t)i * 3 + 0] * d;
    v.y = x[(size_t)i * 3 + 1] * d;
    v.z = x[(size_t)i * 3 + 2] * d;
    v.w = 0.f;
    *reinterpret_cast<float4*>(&xs[(size_t)i * 4]) = v;
}

// group of F lanes per node: acc = in[n] (self) + sum_{e: dst=n} in[src]; epilogue dis/b/relu
template<int F, bool ADD_B, bool RELU>
__global__ void gather_kernel(const float* __restrict__ in, const int* __restrict__ rowptr,
                              const int* __restrict__ csr, const float* __restrict__ dis,
                              const float* __restrict__ b, float* __restrict__ out) {
    constexpr int GPB = 256 / F;
    int tid = threadIdx.x;
    int l = tid & (F - 1);
    int n = blockIdx.x * GPB + (tid / F);
    if (n >= N_NODES) return;
    int beg = rowptr[n], end = rowptr[n + 1];
    float a0 = in[(size_t)n * F + l];   // self loop (already dis[src]-scaled)
    float a1 = 0.f, a2 = 0.f, a3 = 0.f;
    int k = beg;
    for (; k + 3 < end; k += 4) {
        int s0 = csr[k], s1 = csr[k + 1], s2 = csr[k + 2], s3 = csr[k + 3];
        a0 += in[(size_t)s0 * F + l];
        a1 += in[(size_t)s1 * F + l];
        a2 += in[(size_t)s2 * F + l];
        a3 += in[(size_t)s3 * F + l];
    }
    for (; k < end; ++k) a0 += in[(size_t)csr[k] * F + l];
    float v = ((a0 + a1) + (a2 + a3)) * dis[n];
    if (ADD_B) v += b[l];
    if (RELU) v = fmaxf(v, 0.f);
    out[(size_t)n * F + l] = v;
}

// h1[i,f] = relu( sum_k m[i,k]*W1[k,f] + b1[f] ), m is 4-padded (k<3)
__global__ void lin1_kernel(const float* __restrict__ m, const float* __restrict__ W1,
                            const float* __restrict__ b1, float* __restrict__ h1) {
    int i = blockIdx.x * blockDim.x + threadIdx.x;
    if (i >= N_NODES) return;
    float4 mv = *reinterpret_cast<const float4*>(&m[(size_t)i * 4]);
#pragma unroll
    for (int f = 0; f < 32; ++f) {
        float s = b1[f];
        s = fmaf(mv.x, W1[0 * 32 + f], s);
        s = fmaf(mv.y, W1[1 * 32 + f], s);
        s = fmaf(mv.z, W1[2 * 32 + f], s);
        h1[(size_t)i * 32 + f] = fmaxf(s, 0.f);
    }
}

// g[i,:FOUT] = (in[i,:FIN] @ W) * dis[i]
template<int FIN, int FOUT>
__global__ void lin_pre_kernel(const float* __restrict__ in, const float* __restrict__ W,
                               const float* __restrict__ dis, float* __restrict__ g) {
    int i = blockIdx.x * blockDim.x + threadIdx.x;
    if (i >= N_NODES) return;
    float xin[FIN];
#pragma unroll
    for (int k = 0; k < FIN; ++k) xin[k] = in[(size_t)i * FIN + k];
    float d = dis[i];
#pragma unroll
    for (int f = 0; f < FOUT; ++f) {
        float s = 0.f;
#pragma unroll
        for (int k = 0; k < FIN; ++k) s = fmaf(xin[k], W[k * FOUT + f], s);
        g[(size_t)i * FOUT + f] = s * d;
    }
}

// ================= pooling + final linear =================

__global__ void pool_kernel(const float* __restrict__ h, const int* __restrict__ batch,
                            float* __restrict__ pool) {
    __shared__ float lsum[N_GRAPHS * 8];
    __shared__ float lcnt[N_GRAPHS];
    int tid = threadIdx.x;
    for (int j = tid; j < N_GRAPHS * 8; j += blockDim.x) lsum[j] = 0.f;
    for (int j = tid; j < N_GRAPHS; j += blockDim.x) lcnt[j] = 0.f;
    __syncthreads();
    int i = blockIdx.x * blockDim.x + tid;
    if (i < N_NODES) {
        int gm = batch[i];
        const float4* hp = reinterpret_cast<const float4*>(&h[(size_t)i * 8]);
        float4 a = hp[0], bq = hp[1];
        atomicAdd(&lsum[gm * 8 + 0], a.x);
        atomicAdd(&lsum[gm * 8 + 1], a.y);
        atomicAdd(&lsum[gm * 8 + 2], a.z);
        atomicAdd(&lsum[gm * 8 + 3], a.w);
        atomicAdd(&lsum[gm * 8 + 4], bq.x);
        atomicAdd(&lsum[gm * 8 + 5], bq.y);
        atomicAdd(&lsum[gm * 8 + 6], bq.z);
        atomicAdd(&lsum[gm * 8 + 7], bq.w);
        atomicAdd(&lcnt[gm], 1.0f);
    }
    __syncthreads();
    for (int idx = tid; idx < N_GRAPHS * 9; idx += blockDim.x) {
        int gm = idx / 9, j = idx % 9;
        if (lcnt[gm] != 0.f) {
            if (j < 8) atomicAdd(&pool[gm * 8 + j], lsum[gm * 8 + j]);
            else       atomicAdd(&pool[512 + gm], lcnt[gm]);
        }
    }
}

__global__ void final_kernel(const float* __restrict__ pool, const float* __restrict__ Wf,
                             const float* __restrict__ bf, float* __restrict__ out) {
    int t = threadIdx.x;
    if (t >= N_GRAPHS * 3) return;
    int gm = t / 3, c = t % 3;
    float cnt = fmaxf(pool[512 + gm], 1.0f);
    float s = 0.f;
#pragma unroll
    for (int f = 0; f < 8; ++f) s = fmaf(pool[gm * 8 + f] / cnt, Wf[f * 3 + c], s);
    out[t] = s + bf[c];
}

// ================= launch =================

extern "C" void kernel_launch(void* const* d_in, const int* in_sizes, int n_in,
                              void* d_out, int out_size, void* d_ws, size_t ws_size,
                              hipStream_t stream) {
    const float* x     = (const float*)d_in[0];
    const int*   ei    = (const int*)d_in[1];
    const int*   batch = (const int*)d_in[2];
    const float* W1 = (const float*)d_in[3];
    const float* b1 = (const float*)d_in[4];
    const float* W2 = (const float*)d_in[5];
    const float* b2 = (const float*)d_in[6];
    const float* W3 = (const float*)d_in[7];
    const float* b3 = (const float*)d_in[8];
    const float* Wf = (const float*)d_in[9];
    const float* bf = (const float*)d_in[10];

    const int* src = ei;              // edge_index[0] = message sources
    const int* dst = ei + N_EDGES;    // edge_index[1] = aggregation targets

    const int N = N_NODES, E = N_EDGES;

    // workspace layout (ints unless noted); binned region aliases activations
    int*   bin_cur  = (int*)d_ws;                         // NBINS
    int*   bin_base = bin_cur + NBINS;                    // NBINS
    int*   rowptr   = bin_base + NBINS;                   // N+2 (pad keeps binned 8B-aligned)
    float* dis      = (float*)(rowptr + N + 2);           // N
    int*   csr      = (int*)(dis + N);                    // E
    int2*  binned   = (int2*)(csr + E);                   // NBINS*BIN_CAP int2 (28.8MB)
    float* xs       = (float*)binned;                     // alias: 4N   } activations live
    float* m        = xs + (size_t)4 * N;                 // 4N          } only after csr
    float* h1       = m + (size_t)4 * N;                  // 32N         } is built
    float* g        = h1 + (size_t)32 * N;                // 16N
    float* h2       = g + (size_t)16 * N;                 // 16N
    float* pool     = (float*)(binned + (size_t)NBINS * BIN_CAP);  // 576
    float* h3       = xs;                                 // alias (8N), free at layer 3

    const int B = 256;
    const int NB_N = (N + B - 1) / B;

    hipMemsetAsync(bin_cur, 0, NBINS * sizeof(int), stream);
    hipMemsetAsync(pool, 0, N_GRAPHS * 9 * sizeof(float), stream);

    // CSR build: bucket sort (LDS atomics) -> bin scan -> per-bin CSR + dis + rowptr
    bin_kernel<<<NB_BIN, 1024, 0, stream>>>(src, dst, bin_cur, binned);
    binscan_kernel<<<1, 512, 0, stream>>>(bin_cur, bin_base, rowptr);
    csrbuild_kernel<<<NBINS, 1024, 0, stream>>>(binned, bin_cur, bin_base, rowptr, dis, csr);

    // Layer 1: aggregate in 3(4)-dim input space, then 4->32 linear (+b,relu)
    pre1_kernel<<<NB_N, B, 0, stream>>>(x, dis, xs);
    gather_kernel<4, false, false><<<(N + 63) / 64, B, 0, stream>>>(xs, rowptr, csr, dis, b1, m);
    lin1_kernel<<<NB_N, B, 0, stream>>>(m, W1, b1, h1);

    // Layer 2: 32->16 linear (*dis), gather 16, (+b2, relu)
    lin_pre_kernel<32, 16><<<NB_N, B, 0, stream>>>(h1, W2, dis, g);
    gather_kernel<16, true, true><<<(N + 15) / 16, B, 0, stream>>>(g, rowptr, csr, dis, b2, h2);

    // Layer 3: 16->8 linear (*dis), gather 8, (+b3, relu)
    lin_pre_kernel<16, 8><<<NB_N, B, 0, stream>>>(h2, W3, dis, g);
    gather_kernel<8, true, true><<<(N + 31) / 32, B, 0, stream>>>(g, rowptr, csr, dis, b3, h3);

    // Pool + final linear
    pool_kernel<<<NB_N, B, 0, stream>>>(h3, batch, pool);
    final_kernel<<<1, 256, 0, stream>>>(pool, Wf, bf, (float*)d_out);
}